// Round 6
// baseline (99.138 us; speedup 1.0000x reference)
//
#include <hip/hip_runtime.h>

#define KN 64
#define DIN 128
#define DOUT 128
#define EPSF 1e-12f
#define HF (1.0f / 63.0f)

typedef _Float16 h2 __attribute__((ext_vector_type(2)));

#if defined(__has_builtin)
#if __has_builtin(__builtin_amdgcn_fdot2)
#define FDOT2(a, b, c) __builtin_amdgcn_fdot2((a), (b), (c), false)
#endif
#endif
#ifndef FDOT2
static __device__ __forceinline__ float FDOT2(h2 a, h2 b, float c) {
    return c + (float)a.x * (float)b.x + (float)a.y * (float)b.y;
}
#endif

// Table in d_ws: half2 tb[DIN][KN][DOUT] = (y_k, d_k*h)  -> 4 B each
// 128*64*128*4 B = 4 MiB exactly => resident in every per-XCD L2.

__global__ __launch_bounds__(256) void kan_precompute(
    const float* __restrict__ coeffs,   // [DOUT][DIN][KN]
    const float* __restrict__ knots,    // [KN]
    unsigned int* __restrict__ tb)      // [DIN][KN][DOUT] half2
{
    const int i      = blockIdx.x >> 1;          // input dim 0..127
    const int o_base = (blockIdx.x & 1) << 6;    // 0 or 64
    const int wave   = threadIdx.x >> 6;         // 0..3
    const int lane   = threadIdx.x & 63;         // knot index k

    __shared__ float ys[64][65];   // [o_local][k], +1 pad
    __shared__ float ds[64][65];

    float kn  = knots[lane];
    float kn1 = (lane < 63) ? knots[lane + 1] : 0.0f;
    float hk  = kn1 - kn;                 // h[k], valid lanes 0..62
    float hm1 = __shfl_up(hk, 1);         // h[k-1]
    float h1v = __shfl_down(hk, 1);       // h[k+1]
    float hm2 = __shfl_up(hk, 2);         // h[k-2]

    for (int ol = wave; ol < 64; ol += 4) {
        const int o = o_base + ol;
        float y = coeffs[(o * DIN + i) * KN + lane];
        float ynext = __shfl_down(y, 1);
        float delta = (lane < 63) ? (ynext - y) / (hk + EPSF) : 0.0f;
        float dm1 = __shfl_up(delta, 1);      // delta[k-1]

        // interior slopes (lanes 1..62)
        float w1v = 2.0f * hk + hm1;
        float w2v = hk + 2.0f * hm1;
        float denom = w1v / (dm1 + EPSF) + w2v / (delta + EPSF);
        float d = (dm1 * delta > 0.0f) ? (w1v + w2v) / (denom + EPSF) : 0.0f;

        float d1v = __shfl_down(delta, 1);    // delta[1] for lane 0
        if (lane == 0) {
            float df = ((2.0f * hk + h1v) * delta - hk * d1v) / (hk + h1v + EPSF);
            if (df * delta <= 0.0f) df = 0.0f;
            else if (fabsf(df) > 3.0f * fabsf(delta)) df = 3.0f * delta;
            d = df;
        }
        float dm2 = __shfl_up(delta, 2);      // delta[61] for lane 63
        if (lane == 63) {
            float dl = ((2.0f * hm1 + hm2) * dm1 - hm1 * dm2) / (hm1 + hm2 + EPSF);
            if (dl * dm1 <= 0.0f) dl = 0.0f;
            else if (fabsf(dl) > 3.0f * fabsf(dm1)) dl = 3.0f * dm1;
            d = dl;
        }
        ys[ol][lane] = y;
        ds[ol][lane] = d * HF;                // pre-scale slope by h
    }
    __syncthreads();

    // coalesced writes: lane = o_local, 64 lanes x 4 B = 256 B bursts
    const int ol = threadIdx.x & 63;
    const int kb = threadIdx.x >> 6;          // 0..3
    for (int k = kb; k < KN; k += 4) {
        h2 v;
        v.x = (_Float16)ys[ol][k];
        v.y = (_Float16)ds[ol][k];
        tb[(i * KN + k) * DOUT + o_base + ol] = __builtin_bit_cast(unsigned int, v);
    }
}

// Main: wave-uniform classification -> per-wave compacted lists via ballot.
// Wave (bl, ihalf) owns b-row b0+bl, i in [ihalf*64, ihalf*64+64).
// Extrap (x<0 or x>1): 1 x 8 B load of knot row 0 or 63, 2 fdot2.
// Interior:            2 x 8 B loads of knot rows j, j+1, 4 fdot2.
__global__ __launch_bounds__(256) void kan_main(
    const float* __restrict__ x,        // [B][DIN]
    const uint2* __restrict__ tb2,      // [DIN][KN][DOUT/2] pairs of half2
    const float* __restrict__ bias,     // [DOUT]
    float* __restrict__ out)            // [B][DOUT]
{
    const int b0    = blockIdx.x << 1;      // 2 batch rows per block
    const int tid   = threadIdx.x;
    const int wv    = tid >> 6;             // 0..3
    const int lane  = tid & 63;
    const int bl    = wv >> 1;              // local b row
    const int ihalf = wv & 1;               // i-range half

    __shared__ uint4  listI[4][64];         // {w01, w23, uint2-offset, pad}
    __shared__ uint2  listE[4][64];         // {w01, uint2-offset}
    __shared__ float2 red[2][64];

    // ---- Phase 1: this wave's lane L handles i = ihalf*64 + L ----
    const int i = (ihalf << 6) + lane;
    float xv = x[(b0 + bl) * DIN + i];
    const bool ext = (xv < 0.0f) || (xv > 1.0f);
    unsigned long long mE = __ballot(ext);
    const int nE = __popcll(mE);
    const int nI = 64 - nE;
    const unsigned long long below = (1ULL << lane) - 1ULL;

    if (ext) {
        int slot = __popcll(mE & below);
        float tt = (xv < 0.0f) ? xv * 63.0f : (xv - 1.0f) * 63.0f;
        int k = (xv < 0.0f) ? 0 : 63;
        h2 w01; w01.x = (_Float16)1.0f; w01.y = (_Float16)tt;
        uint2 e;
        e.x = __builtin_bit_cast(unsigned int, w01);
        e.y = (unsigned)(((i << 6) + k) << 6);       // uint2-index of row base
        listE[wv][slot] = e;
    } else {
        int slot = __popcll((~mE) & below);
        int idx = (int)(xv * 63.0f);
        idx = idx > 62 ? 62 : idx;
        float t = xv * 63.0f - (float)idx;
        float t2 = t * t, t3 = t2 * t;
        float w0 = 2.0f * t3 - 3.0f * t2 + 1.0f;
        float w1 = t3 - 2.0f * t2 + t;               // slope pre-scaled by h
        float w2 = 3.0f * t2 - 2.0f * t3;
        float w3 = t3 - t2;
        h2 w01; w01.x = (_Float16)w0; w01.y = (_Float16)w1;
        h2 w23; w23.x = (_Float16)w2; w23.y = (_Float16)w3;
        uint4 q;
        q.x = __builtin_bit_cast(unsigned int, w01);
        q.y = __builtin_bit_cast(unsigned int, w23);
        q.z = (unsigned)(((i << 6) + idx) << 6);     // uint2-index of row j
        q.w = 0u;
        listI[wv][slot] = q;
    }
    // No barrier needed: lists are written and read by the SAME wave
    // (compiler orders ds_write -> ds_read via lgkmcnt).

    // ---- Phase 2: branchless compacted loops ----
    float acc0 = 0.0f, acc1 = 0.0f;
    const uint2* tp = tb2 + lane;           // lane -> o = 2*lane, 2*lane+1

    #pragma unroll 4
    for (int n = 0; n < nE; ++n) {
        uint2 e = listE[wv][n];
        h2 w01 = __builtin_bit_cast(h2, e.x);
        uint2 r = tp[e.y];                  // knot row 0 or 63
        acc0 = FDOT2(w01, __builtin_bit_cast(h2, r.x), acc0);
        acc1 = FDOT2(w01, __builtin_bit_cast(h2, r.y), acc1);
    }

    #pragma unroll 4
    for (int n = 0; n < nI; ++n) {
        uint4 q = listI[wv][n];
        h2 w01 = __builtin_bit_cast(h2, q.x);
        h2 w23 = __builtin_bit_cast(h2, q.y);
        uint2 rA = tp[q.z];                 // knot row j
        uint2 rB = tp[q.z + 64];            // knot row j+1
        acc0 = FDOT2(w01, __builtin_bit_cast(h2, rA.x), acc0);
        acc0 = FDOT2(w23, __builtin_bit_cast(h2, rB.x), acc0);
        acc1 = FDOT2(w01, __builtin_bit_cast(h2, rA.y), acc1);
        acc1 = FDOT2(w23, __builtin_bit_cast(h2, rB.y), acc1);
    }

    // ---- Cross-wave reduce (ihalf 1 -> ihalf 0), then store ----
    if (ihalf) red[bl][lane] = make_float2(acc0, acc1);
    __syncthreads();
    if (!ihalf) {
        float2 r2 = red[bl][lane];
        const int o0 = lane << 1;
        float2 bo = *reinterpret_cast<const float2*>(&bias[o0]);
        float2 res;
        res.x = acc0 + r2.x + bo.x;
        res.y = acc1 + r2.y + bo.y;
        *reinterpret_cast<float2*>(&out[(b0 + bl) * DOUT + o0]) = res;
    }
}

extern "C" void kernel_launch(void* const* d_in, const int* in_sizes, int n_in,
                              void* d_out, int out_size, void* d_ws, size_t ws_size,
                              hipStream_t stream) {
    const float* x      = (const float*)d_in[0];   // 4096*128
    const float* coeffs = (const float*)d_in[1];   // 128*128*64
    const float* bias   = (const float*)d_in[2];   // 128
    const float* knots  = (const float*)d_in[3];   // 64
    float* out = (float*)d_out;
    unsigned int* tb = (unsigned int*)d_ws;        // 4 MiB knot table

    kan_precompute<<<256, 256, 0, stream>>>(coeffs, knots, tb);
    kan_main<<<2048, 256, 0, stream>>>(x, (const uint2*)tb, bias, out);
}